// Round 11
// baseline (387.847 us; speedup 1.0000x reference)
//
#include <hip/hip_runtime.h>
#include <hip/hip_bf16.h>

// ---------------------------------------------------------------------------
// BasicTransformerBlock (l2-attention x2 + GEGLU FFN), MI355X gfx950
// Round 21: attn wave-local de-serialization (pipes summed ~= dur -> no
// overlap inside the c-loop chain QK->exp->PV):
//  (1) lr via MFMA row-sum: sacc = mfma(pa, ones, sacc) replaces 16 VALU
//      adds/c + final shfl; denominator now bf16-P consistent with numerator.
//  (2) software-pipelined c-loop (T15): QK(c+1) issued under exp/PV(c),
//      double s-state, statically unrolled. Barriers/staging untouched.
// Rest identical to round 20 (381.6us best).
// ---------------------------------------------------------------------------

typedef short bf16x8 __attribute__((ext_vector_type(8)));
typedef float f32x4 __attribute__((ext_vector_type(4)));
typedef unsigned short u16;
typedef unsigned int u32;

__device__ __forceinline__ float bf2f(u16 u) {
    return __uint_as_float(((u32)u) << 16);
}
__device__ __forceinline__ u16 f2bf(float f) {
    u32 u = __float_as_uint(f);
    u32 rb = ((u >> 16) & 1u) + 0x7fffu;   // round-to-nearest-even
    return (u16)((u + rb) >> 16);
}
// tanh-form gelu: x * sigmoid(1.59577(x + 0.044715 x^3)); |err| <~1e-3.
__device__ __forceinline__ float gelu_fast(float x) {
    float y = 1.5957691216f * (x + 0.044715f * x * x * x);
    return x / (1.f + __expf(-y));
}
__device__ __forceinline__ void gl2lds16(const u16* g, u16* l) {
    __builtin_amdgcn_global_load_lds(
        (const __attribute__((address_space(1))) void*)(unsigned long long)(uintptr_t)g,
        (__attribute__((address_space(3))) void*)(unsigned long long)(uintptr_t)l,
        16, 0, 0);
}

// ---------------------------------------------------------------------------
// Merged weight transpose: 8 segments of fp32 [R][C] -> bf16 [C][R].
struct TArgs {
    const float* src[8];
    u16* dst[8];
    int R[8], C[8];
    int start[9];
};
__global__ __launch_bounds__(256) void transpose_multi(TArgs a) {
    __shared__ float tile[32][33];
    int bid = blockIdx.x;
    int s = 0;
    while (bid >= a.start[s + 1]) s++;
    int local = bid - a.start[s];
    int R = a.R[s], C = a.C[s];
    int tx = C >> 5;
    int bx = local % tx, by = local / tx;
    const float* in = a.src[s];
    u16* out = a.dst[s];
    int t = threadIdx.x;
    int c = t & 31, r0 = (t >> 5) * 4;
#pragma unroll
    for (int i = 0; i < 4; i++)
        tile[r0 + i][c] = in[(size_t)(by * 32 + r0 + i) * C + bx * 32 + c];
    __syncthreads();
#pragma unroll
    for (int i = 0; i < 4; i++)
        out[(size_t)(bx * 32 + r0 + i) * R + by * 32 + c] = f2bf(tile[c][r0 + i]);
}

// ---------------------------------------------------------------------------
// LayerNorm: x fp32 [rows][512] -> out bf16. One WAVE per row (4 rows/block),
// 8 elems/lane, shfl-only reduction (no LDS, no barrier). Grid 2048.
__global__ __launch_bounds__(256) void ln_kernel(const float* __restrict__ x,
                                                 const float* __restrict__ w,
                                                 const float* __restrict__ b,
                                                 u16* __restrict__ out) {
    int t = threadIdx.x;
    int wave = t >> 6, lane = t & 63;
    int row = blockIdx.x * 4 + wave;
    const float* xr = x + (size_t)row * 512 + lane * 8;
    float4 v0 = *(const float4*)xr;
    float4 v1 = *(const float4*)(xr + 4);
    float s1 = (v0.x + v0.y) + (v0.z + v0.w) + (v1.x + v1.y) + (v1.z + v1.w);
    float s2 = (v0.x * v0.x + v0.y * v0.y) + (v0.z * v0.z + v0.w * v0.w) +
               (v1.x * v1.x + v1.y * v1.y) + (v1.z * v1.z + v1.w * v1.w);
#pragma unroll
    for (int m = 1; m < 64; m <<= 1) {
        s1 += __shfl_xor(s1, m);
        s2 += __shfl_xor(s2, m);
    }
    float mu = s1 * (1.f / 512.f);
    float var = s2 * (1.f / 512.f) - mu * mu;
    float rs = rsqrtf(var + 1e-5f);
    const float* wp = w + lane * 8;
    const float* bp = b + lane * 8;
    float4 w0 = *(const float4*)wp;
    float4 w1 = *(const float4*)(wp + 4);
    float4 b0 = *(const float4*)bp;
    float4 b1 = *(const float4*)(bp + 4);
    u16 r[8];
    r[0] = f2bf((v0.x - mu) * rs * w0.x + b0.x);
    r[1] = f2bf((v0.y - mu) * rs * w0.y + b0.y);
    r[2] = f2bf((v0.z - mu) * rs * w0.z + b0.z);
    r[3] = f2bf((v0.w - mu) * rs * w0.w + b0.w);
    r[4] = f2bf((v1.x - mu) * rs * w1.x + b1.x);
    r[5] = f2bf((v1.y - mu) * rs * w1.y + b1.y);
    r[6] = f2bf((v1.z - mu) * rs * w1.z + b1.z);
    r[7] = f2bf((v1.w - mu) * rs * w1.w + b1.w);
    *(uint4*)(out + (size_t)row * 512 + lane * 8) = *(uint4*)r;
}

// ---------------------------------------------------------------------------
// ff1+GEGLU fused rect GEMM: A [8192][512] bf16, BT = ff1^T [4096][512].
// Epilogue: g = a * gelu(gate) -> gbuf [8192][2048] bf16.
__global__ __launch_bounds__(256) void gemm_ff1(const u16* __restrict__ A,
                                                const u16* __restrict__ BT,
                                                const float* __restrict__ bias,
                                                u16* __restrict__ gout,
                                                int K) {
    __shared__ u16 As[2][128 * 32];
    __shared__ u16 Bs[2][128 * 32];   // rows 0-63 = a-half, 64-127 = gate-half
    int t = threadIdx.x;
    int wave = t >> 6, lane = t & 63, quad = lane >> 4, l16 = lane & 15;
    int m0 = blockIdx.x * 128, n0 = blockIdx.y * 64;
    f32x4 aacc[2][4], gacc[2][4];
#pragma unroll
    for (int i = 0; i < 2; i++)
#pragma unroll
        for (int j = 0; j < 4; j++) {
            aacc[i][j] = (f32x4){0.f, 0.f, 0.f, 0.f};
            gacc[i][j] = (f32x4){0.f, 0.f, 0.f, 0.f};
        }
    const u16* Ag = A + (size_t)(m0 + wave * 32 + (lane >> 2)) * K + (lane & 3) * 8;
    int brow = (wave < 2) ? (n0 + wave * 32) : (2048 + n0 + (wave - 2) * 32);
    const u16* Bg = BT + (size_t)(brow + (lane >> 2)) * K + (lane & 3) * 8;
    int lo = wave * 32 * 32;
    const size_t rstep = (size_t)16 * K;
    gl2lds16(Ag, &As[0][lo]);
    gl2lds16(Ag + rstep, &As[0][lo + 16 * 32]);
    gl2lds16(Bg, &Bs[0][lo]);
    gl2lds16(Bg + rstep, &Bs[0][lo + 16 * 32]);
    int buf = 0;
    for (int k0 = 0; k0 < K; k0 += 32, buf ^= 1) {
        int kn = (k0 + 32 < K) ? (k0 + 32) : k0;
        int nb = buf ^ 1;
        asm volatile("s_waitcnt lgkmcnt(0)\n\ts_barrier" ::: "memory");
        gl2lds16(Ag + kn, &As[nb][lo]);
        gl2lds16(Ag + kn + rstep, &As[nb][lo + 16 * 32]);
        gl2lds16(Bg + kn, &Bs[nb][lo]);
        gl2lds16(Bg + kn + rstep, &Bs[nb][lo + 16 * 32]);
        asm volatile("s_waitcnt vmcnt(4)\n\ts_barrier" ::: "memory");
        bf16x8 a[2];
#pragma unroll
        for (int i = 0; i < 2; i++)
            a[i] = *(const bf16x8*)&As[buf][(wave * 32 + i * 16 + l16) * 32 + quad * 8];
#pragma unroll
        for (int j = 0; j < 4; j++) {
            bf16x8 ba = *(const bf16x8*)&Bs[buf][(j * 16 + l16) * 32 + quad * 8];
            bf16x8 bg = *(const bf16x8*)&Bs[buf][(64 + j * 16 + l16) * 32 + quad * 8];
#pragma unroll
            for (int i = 0; i < 2; i++) {
                aacc[i][j] = __builtin_amdgcn_mfma_f32_16x16x32_bf16(a[i], ba, aacc[i][j], 0, 0, 0);
                gacc[i][j] = __builtin_amdgcn_mfma_f32_16x16x32_bf16(a[i], bg, gacc[i][j], 0, 0, 0);
            }
        }
    }
    asm volatile("s_waitcnt vmcnt(0)" ::: "memory");   // drain DMA before endpgm
    int row_base = m0 + wave * 32 + quad * 4;
#pragma unroll
    for (int j = 0; j < 4; j++) {
        int col = n0 + j * 16 + l16;
        float ba = bias[col];
        float bg = bias[2048 + col];
#pragma unroll
        for (int i = 0; i < 2; i++) {
#pragma unroll
            for (int r = 0; r < 4; r++) {
                int row = row_base + i * 16 + r;
                float av = aacc[i][j][r] + ba;
                float gv = gacc[i][j][r] + bg;
                gout[(size_t)row * 2048 + col] = f2bf(av * gelu_fast(gv));
            }
        }
    }
}

// ---------------------------------------------------------------------------
// q/v projection GEMM, 128x128 tile: A [8192][512], BT [1024][512].
// Block is entirely q (n0<512) or entirely v. Fused AA per j-half.
__global__ __launch_bounds__(256) void gemm_qv(const u16* __restrict__ A,
                                               const u16* __restrict__ BT,
                                               const float* __restrict__ bias,
                                               const float* __restrict__ bias2,
                                               u16* __restrict__ outb,
                                               u16* __restrict__ outb2,
                                               float* __restrict__ aa,
                                               int K) {
    __shared__ u16 As[2][128 * 32];
    __shared__ u16 Bs[2][128 * 32];
    int t = threadIdx.x;
    int wave = t >> 6, lane = t & 63, quad = lane >> 4, l16 = lane & 15;
    int m0 = blockIdx.x * 128, n0 = blockIdx.y * 128;
    f32x4 acc[2][8];
#pragma unroll
    for (int i = 0; i < 2; i++)
#pragma unroll
        for (int j = 0; j < 8; j++) acc[i][j] = (f32x4){0.f, 0.f, 0.f, 0.f};
    const u16* Ag = A + (size_t)(m0 + wave * 32 + (lane >> 2)) * K + (lane & 3) * 8;
    const u16* Bg = BT + (size_t)(n0 + wave * 32 + (lane >> 2)) * K + (lane & 3) * 8;
    int lo = wave * 32 * 32;
    const size_t rstep = (size_t)16 * K;
    gl2lds16(Ag, &As[0][lo]);
    gl2lds16(Ag + rstep, &As[0][lo + 16 * 32]);
    gl2lds16(Bg, &Bs[0][lo]);
    gl2lds16(Bg + rstep, &Bs[0][lo + 16 * 32]);
    int buf = 0;
    for (int k0 = 0; k0 < K; k0 += 32, buf ^= 1) {
        int kn = (k0 + 32 < K) ? (k0 + 32) : k0;
        int nb = buf ^ 1;
        asm volatile("s_waitcnt lgkmcnt(0)\n\ts_barrier" ::: "memory");
        gl2lds16(Ag + kn, &As[nb][lo]);
        gl2lds16(Ag + kn + rstep, &As[nb][lo + 16 * 32]);
        gl2lds16(Bg + kn, &Bs[nb][lo]);
        gl2lds16(Bg + kn + rstep, &Bs[nb][lo + 16 * 32]);
        asm volatile("s_waitcnt vmcnt(4)\n\ts_barrier" ::: "memory");
        bf16x8 a[2];
#pragma unroll
        for (int i = 0; i < 2; i++)
            a[i] = *(const bf16x8*)&As[buf][(wave * 32 + i * 16 + l16) * 32 + quad * 8];
#pragma unroll
        for (int j = 0; j < 8; j++) {
            bf16x8 b = *(const bf16x8*)&Bs[buf][(j * 16 + l16) * 32 + quad * 8];
#pragma unroll
            for (int i = 0; i < 2; i++)
                acc[i][j] = __builtin_amdgcn_mfma_f32_16x16x32_bf16(a[i], b, acc[i][j], 0, 0, 0);
        }
    }
    asm volatile("s_waitcnt vmcnt(0)" ::: "memory");   // drain DMA before endpgm
    int row_base = m0 + wave * 32 + quad * 4;
    bool isq = (n0 < 512);
    float ssq[2][2][4];   // [jh][i][r]
#pragma unroll
    for (int jh = 0; jh < 2; jh++)
#pragma unroll
        for (int i = 0; i < 2; i++)
#pragma unroll
            for (int r = 0; r < 4; r++) ssq[jh][i][r] = 0.f;
#pragma unroll
    for (int j = 0; j < 8; j++) {
        int col = n0 + j * 16 + l16;
        float bv = isq ? bias[col] : bias2[col - 512];
        int jh = j >> 2;
#pragma unroll
        for (int i = 0; i < 2; i++) {
            int rowA = row_base + i * 16;
            if (isq) {
                int hh = col >> 6, d = col & 63;
#pragma unroll
                for (int r = 0; r < 4; r++) {
                    int row = rowA + r;
                    float v = acc[i][j][r] + bv;
                    ssq[jh][i][r] += v * v;
                    outb[((size_t)((row >> 11) * 8 + hh) * 2048 + (row & 2047)) * 64 + d] = f2bf(v);
                }
            } else {
                int c2 = col - 512;
                int hh = c2 >> 6, d = c2 & 63;
                int n = rowA & 2047;
                int a4 = (n >> 2) & 7;
                int ncol = (n & ~31) + ((a4 & 3) << 3) + ((a4 >> 2) << 2);
                u32 plo = (u32)f2bf(acc[i][j][0] + bv) | ((u32)f2bf(acc[i][j][1] + bv) << 16);
                u32 phi = (u32)f2bf(acc[i][j][2] + bv) | ((u32)f2bf(acc[i][j][3] + bv) << 16);
                uint2 pk; pk.x = plo; pk.y = phi;
                *(uint2*)&outb2[((size_t)((rowA >> 11) * 8 + hh) * 64 + d) * 2048 + ncol] = pk;
            }
        }
    }
    // fused AA (aa = 0.125*log2e*||q||^2), one head per j-half
    if (isq) {
#pragma unroll
        for (int jh = 0; jh < 2; jh++) {
            int hh = (n0 >> 6) + jh;
#pragma unroll
            for (int i = 0; i < 2; i++) {
#pragma unroll
                for (int r = 0; r < 4; r++) {
                    float s = ssq[jh][i][r];
                    s += __shfl_xor(s, 1); s += __shfl_xor(s, 2);
                    s += __shfl_xor(s, 4); s += __shfl_xor(s, 8);
                    if (l16 == 0) {
                        int row = row_base + i * 16 + r;
                        aa[(size_t)((row >> 11) * 8 + hh) * 2048 + (row & 2047)] = s * 0.18033688f;
                    }
                }
            }
        }
    }
}

// ---------------------------------------------------------------------------
// Rect 128x64 MFMA GEMM (double-buffered, vmcnt(3)): fp32 out = acc+bias+res.
template <int MODE>
__global__ __launch_bounds__(256) void gemm_rect(const u16* __restrict__ A,
                                                 const u16* __restrict__ BT,
                                                 const float* __restrict__ bias,
                                                 const float* __restrict__ res,
                                                 float* __restrict__ outf,
                                                 int M, int N, int K) {
    __shared__ u16 As[2][128 * 32];
    __shared__ u16 Bs[2][64 * 32];
    int t = threadIdx.x;
    int wave = t >> 6, lane = t & 63, quad = lane >> 4, l16 = lane & 15;
    int m0 = blockIdx.x * 128, n0 = blockIdx.y * 64;
    f32x4 acc[2][4];
#pragma unroll
    for (int i = 0; i < 2; i++)
#pragma unroll
        for (int j = 0; j < 4; j++) acc[i][j] = (f32x4){0.f, 0.f, 0.f, 0.f};
    const u16* Ag = A + (size_t)(m0 + wave * 32 + (lane >> 2)) * K + (lane & 3) * 8;
    const u16* Bg = BT + (size_t)(n0 + wave * 16 + (lane >> 2)) * K + (lane & 3) * 8;
    int loA = wave * 32 * 32;
    int loB = wave * 16 * 32;
    const size_t rstep = (size_t)16 * K;
    gl2lds16(Ag, &As[0][loA]);
    gl2lds16(Ag + rstep, &As[0][loA + 16 * 32]);
    gl2lds16(Bg, &Bs[0][loB]);
    int buf = 0;
    for (int k0 = 0; k0 < K; k0 += 32, buf ^= 1) {
        int kn = (k0 + 32 < K) ? (k0 + 32) : k0;
        int nb = buf ^ 1;
        asm volatile("s_waitcnt lgkmcnt(0)\n\ts_barrier" ::: "memory");
        gl2lds16(Ag + kn, &As[nb][loA]);
        gl2lds16(Ag + kn + rstep, &As[nb][loA + 16 * 32]);
        gl2lds16(Bg + kn, &Bs[nb][loB]);
        asm volatile("s_waitcnt vmcnt(3)\n\ts_barrier" ::: "memory");
        bf16x8 a[2], b[4];
#pragma unroll
        for (int i = 0; i < 2; i++)
            a[i] = *(const bf16x8*)&As[buf][(wave * 32 + i * 16 + l16) * 32 + quad * 8];
#pragma unroll
        for (int j = 0; j < 4; j++)
            b[j] = *(const bf16x8*)&Bs[buf][(j * 16 + l16) * 32 + quad * 8];
#pragma unroll
        for (int i = 0; i < 2; i++)
#pragma unroll
            for (int j = 0; j < 4; j++)
                acc[i][j] = __builtin_amdgcn_mfma_f32_16x16x32_bf16(a[i], b[j], acc[i][j], 0, 0, 0);
    }
    asm volatile("s_waitcnt vmcnt(0)" ::: "memory");   // drain DMA before endpgm
    int row_base = m0 + wave * 32 + quad * 4;
#pragma unroll
    for (int j = 0; j < 4; j++) {
        int col = n0 + j * 16 + l16;
        float bv = bias[col];
#pragma unroll
        for (int i = 0; i < 2; i++) {
            int rowA = row_base + i * 16;
#pragma unroll
            for (int r = 0; r < 4; r++) {
                size_t idx = (size_t)(rowA + r) * N + col;
                outf[idx] = acc[i][j][r] + bv + res[idx];
            }
        }
    }
}

// ---------------------------------------------------------------------------
// MFMA flash L2-attention, S^T formulation, 2 i-subtiles/wave, swizzled LDS,
// 128-KV tiles, ci-free exp2 softmax. Round-21: software-pipelined c-loop
// (QK(c+1) under exp/PV(c)) + lr via MFMA row-sum (P @ ones -> sacc).
// Grid 512: bh = bid & 31 (xcd = bh%8), itile = bid >> 5 (16 x 128 q-rows).
__global__ __launch_bounds__(256) void attn_mfma(const u16* __restrict__ qbuf,
                                                 const u16* __restrict__ vtp,
                                                 const float* __restrict__ aas,
                                                 u16* __restrict__ out) {
    // per buffer: [0..8191] = Q-tile 128x64 (swz), [8192..16383] = V-tile 64x128 (swz)
    __shared__ u16 L[2][16384];
    int bid = blockIdx.x;
    int bh = bid & 31;
    int itile = bid >> 5;
    const u16* qb = qbuf + (size_t)bh * 2048 * 64;
    const u16* vtb = vtp + (size_t)bh * 64 * 2048;
    const float* aab = aas + (size_t)bh * 2048;
    int t = threadIdx.x;
    int wave = t >> 6, lane = t & 63, quad = lane >> 4, l16 = lane & 15;
    int sw7 = l16 & 7;
    int ibase = itile * 128 + wave * 32;

    bf16x8 qf[2][2];
    f32x4 O[2][4];
    f32x4 sacc[2];
#pragma unroll
    for (int st = 0; st < 2; st++) {
        const u16* qr = qb + (size_t)(ibase + st * 16 + l16) * 64;
        qf[st][0] = *(const bf16x8*)(qr + quad * 8);
        qf[st][1] = *(const bf16x8*)(qr + 32 + quad * 8);
        sacc[st] = (f32x4){0.f, 0.f, 0.f, 0.f};
#pragma unroll
        for (int nt = 0; nt < 4; nt++) O[st][nt] = (f32x4){0.f, 0.f, 0.f, 0.f};
    }
    bf16x8 vones;
    {
        u32* vo = (u32*)&vones;
        vo[0] = vo[1] = vo[2] = vo[3] = 0x3F803F80u;   // 8 x bf16(1.0)
    }

    // staging geometry: 4 Q slots (128 rows x 8 slots) + 4 V slots (64 rows x 16 slots)
    int qrow[4], qcs[4], qwof[4], vrow[4], vsl[4], vwof[4];
#pragma unroll
    for (int k = 0; k < 4; k++) {
        int s = t + k * 256;
        qrow[k] = s >> 3; qcs[k] = s & 7;
        qwof[k] = qrow[k] * 64 + 8 * (qcs[k] ^ (qrow[k] & 7));
        vrow[k] = s >> 4; vsl[k] = s & 15;
        vwof[k] = 8192 + vrow[k] * 128 + 8 * ((vsl[k] & 8) | ((vsl[k] & 7) ^ (vrow[k] & 7)));
    }
    // prologue: tile j0 = 0 into buf 0
#pragma unroll
    for (int k = 0; k < 4; k++) {
        *(uint4*)&L[0][qwof[k]] = *(const uint4*)(qb + (size_t)qrow[k] * 64 + qcs[k] * 8);
        *(uint4*)&L[0][vwof[k]] = *(const uint4*)(vtb + (size_t)vrow[k] * 2048 + vsl[k] * 8);
    }
    __syncthreads();

    const float C0 = 0.36067376f;   // 0.25 * log2(e)
    for (int it = 0; it < 16; ++it) {
        int cur = it & 1;
        int j0 = it << 7;
        uint4 pq[4], pv[4];
        bool more = (it + 1 < 16);
        if (more) {
            int j0n = j0 + 128;
#pragma unroll
            for (int k = 0; k < 4; k++) {
                pq[k] = *(const uint4*)(qb + (size_t)(j0n + qrow[k]) * 64 + qcs[k] * 8);
                pv[k] = *(const uint4*)(vtb + (size_t)vrow[k] * 2048 + j0n + vsl[k] * 8);
            }
        }
        const u16* Q = &L[cur][0];
        const u16* V = &L[cur][8192];

        auto QK = [&](int c, f32x4 s0o[2], f32x4 s1o[2]) {
            int r10 = c * 32 + l16, r20 = c * 32 + 16 + l16;
            bf16x8 a10 = *(const bf16x8*)&Q[r10 * 64 + 8 * (quad ^ sw7)];
            bf16x8 a11 = *(const bf16x8*)&Q[r10 * 64 + 8 * ((4 + quad) ^ sw7)];
            bf16x8 a20 = *(const bf16x8*)&Q[r20 * 64 + 8 * (quad ^ sw7)];
            bf16x8 a21 = *(const bf16x8*)&Q[r20 * 64 + 8 * ((4 + quad) ^ sw7)];
            __builtin_amdgcn_s_setprio(1);
#pragma unroll
            for (int st = 0; st < 2; st++) {
                f32x4 z = {0.f, 0.f, 0.f, 0.f};
                s0o[st] = __builtin_amdgcn_mfma_f32_16x16x32_bf16(a10, qf[st][0], z, 0, 0, 0);
                s0o[st] = __builtin_amdgcn_mfma_f32_16x16x32_bf16(a11, qf[st][1], s0o[st], 0, 0, 0);
                s1o[st] = __builtin_amdgcn_mfma_f32_16x16x32_bf16(a20, qf[st][0], z, 0, 0, 0);
                s1o[st] = __builtin_amdgcn_mfma_f32_16x16x32_bf16(a21, qf[st][1], s1o[st], 0, 0, 0);
            }
            __builtin_amdgcn_s_setprio(0);
        };

        f32x4 sc0[2], sc1[2], sn0[2], sn1[2];
        QK(0, sc0, sc1);
#pragma unroll
        for (int c = 0; c < 4; c++) {
            if (c < 3) QK(c + 1, sn0, sn1);   // issue next QK under this c's exp/PV
            float4 aav0 = *(const float4*)(aab + j0 + c * 32 + quad * 4);
            float4 aav1 = *(const float4*)(aab + j0 + c * 32 + 16 + quad * 4);
            bf16x8 pa[2];
#pragma unroll
            for (int st = 0; st < 2; st++) {
                float p0 = __builtin_amdgcn_exp2f(fmaf(sc0[st][0], C0, -aav0.x));
                float p1 = __builtin_amdgcn_exp2f(fmaf(sc0[st][1], C0, -aav0.y));
                float p2 = __builtin_amdgcn_exp2f(fmaf(sc0[st][2], C0, -aav0.z));
                float p3 = __builtin_amdgcn_exp2f(fmaf(sc0[st][3], C0, -aav0.w));
                float p4 = __builtin_amdgcn_exp2f(fmaf(sc1[st][0], C0, -aav1.x));
                float p5 = __builtin_amdgcn_exp2f(fmaf(sc1[st][1], C0, -aav1.y));
                float p6 = __builtin_amdgcn_exp2f(fmaf(sc1[st][2], C0, -aav1.z));
                float p7 = __builtin_amdgcn_exp2f(fmaf(sc1[st][3], C0, -aav1.w));
                u32* pu = (u32*)&pa[st];
                pu[0] = __builtin_amdgcn_perm(__float_as_uint(p1), __float_as_uint(p0), 0x07060302u);
                pu[1] = __builtin_amdgcn_perm(__float_as_uint(p3), __float_as_uint(p2), 0x07060302u);
                pu[2] = __builtin_amdgcn_perm(__float_as_uint(p5), __float_as_uint(p4), 0x07060302u);
                pu[3] = __builtin_amdgcn_perm(__float_as_uint(p7), __float_as_uint(p6), 0x07060302u);
            }
            __builtin_amdgcn_s_setprio(1);
#pragma unroll
            for (int nt = 0; nt < 4; nt++) {
                int sl = c * 4 + quad;
                bf16x8 vf = *(const bf16x8*)&V[(nt * 16 + l16) * 128 + 8 * ((sl & 8) | ((sl & 7) ^ sw7))];
                O[0][nt] = __builtin_amdgcn_mfma_f32_16x16x32_bf16(pa[0], vf, O[0][nt], 0, 0, 0);
                O[1][nt] = __builtin_amdgcn_mfma_f32_16x16x32_bf16(pa[1], vf, O[1][nt], 0, 0, 0);
            }
            // lr via MFMA row-sum: D[i][n] = sum_j P[i][j] (denominator, bf16-P
            // consistent with the PV numerator)
            sacc[0] = __builtin_amdgcn_mfma_f32_16x16x32_bf16(pa[0], vones, sacc[0], 0, 0, 0);
            sacc[1] = __builtin_amdgcn_mfma_f32_16x16x32_bf16(pa[1], vones, sacc[1], 0, 0, 0);
            __builtin_amdgcn_s_setprio(0);
#pragma unroll
            for (int st = 0; st < 2; st++) { sc0[st] = sn0[st]; sc1[st] = sn1[st]; }
        }
        if (more) {
            u16* D = &L[cur ^ 1][0];
#pragma unroll
            for (int k = 0; k < 4; k++) {
                *(uint4*)&D[qwof[k]] = pq[k];
                *(uint4*)&D[vwof[k]] = pv[k];
            }
        }
        __syncthreads();
    }

    int b = bh >> 3, h = bh & 7;
#pragma unroll
    for (int st = 0; st < 2; st++) {
#pragma unroll
        for (int r = 0; r < 4; r++) {
            float invr = 1.f / sacc[st][r];
            size_t row = (size_t)(b * 2048 + ibase + st * 16 + quad * 4 + r);
            u16* o = out + row * 512 + h * 64 + l16;
            o[0]  = f2bf(O[st][0][r] * invr);
            o[16] = f2bf(O[st][1][r] * invr);
            o[32] = f2bf(O[st][2][r] * invr);
            o[48] = f2bf(O[st][3][r] * invr);
        }
    }
}

// ---------------------------------------------------------------------------
extern "C" void kernel_launch(void* const* d_in, const int* in_sizes, int n_in,
                              void* d_out, int out_size, void* d_ws, size_t ws_size,
                              hipStream_t stream) {
    const float* x      = (const float*)d_in[0];
    const float* sa_w   = (const float*)d_in[1];
    const float* sa_b   = (const float*)d_in[2];
    const float* ca_w   = (const float*)d_in[3];
    const float* ca_b   = (const float*)d_in[4];
    const float* ffn_w  = (const float*)d_in[5];
    const float* ffn_b  = (const float*)d_in[6];
    const float* a1_wq  = (const float*)d_in[7];
    const float* a1_bq  = (const float*)d_in[8];
    const float* a1_wv  = (const float*)d_in[9];
    const float* a1_bv  = (const float*)d_in[10];
    const float* a1_wo  = (const float*)d_in[11];
    const float* a1_bo  = (const float*)d_in[12];
    const float* a2_wq  = (const float*)d_in[13];
    const float* a2_bq  = (const float*)d_in[14];
    const float* a2_wv  = (const float*)d_in[15];
    const float* a2_bv  = (const float*)d_in[16];
    const float* a2_wo  = (const float*)d_in[17];
    const float* a2_bo  = (const float*)d_in[18];
    const float* ff_w1  = (const float*)d_in[19];
    const float* ff_b1  = (const float*)d_in[20];
    const float* ff_w2  = (const float*)d_in[21];
    const float* ff_b2  = (const float*)d_in[22];

    char* ws = (char*)d_ws;
    const size_t MB = 1ull << 20;
    float* x_res   = (float*)(ws);              // 16 MB fp32 residual stream
    u16* xn        = (u16*)(ws + 16 * MB);      // 8 MB normed activations (bf16)
    u16* wT_a1qv   = (u16*)(ws + 24 * MB);      // 1 MB [1024][512] (wq^T | wv^T)
    u16* wT_a2qv   = (u16*)(ws + 25 * MB);      // 1 MB
    u16* wT_a1o    = (u16*)(ws + 26 * MB);      // 0.5 MB
    u16* wT_a2o    = (u16*)(ws + 26 * MB + 512 * 1024);
    u16* wT_ff1    = (u16*)(ws + 27 * MB);      // 4 MB [4096][512]
    u16* wT_ff2    = (u16*)(ws + 31 * MB);      // 2 MB [512][2048]
    u16* qbuf      = (u16*)(ws + 34 * MB);      // 8 MB [bh][2048][64]
    u16* vtp       = (u16*)(ws + 42 * MB);      // 8 MB [bh][64][2048] (j-permuted)
    float* aab     = (float*)(ws + 50 * MB);    // 256 KB (0.125*log2e*||q||^2)
    u16* attn_o    = (u16*)(ws + 51 * MB);      // 8 MB bf16 [8192][512]
    u16* gbuf      = (u16*)(ws + 60 * MB);      // 32 MB [8192][2048] bf16

    (void)in_sizes; (void)n_in; (void)out_size; (void)ws_size;

    // merged weight transposes (fp32 -> bf16 [N][K]); q|v concatenated
    TArgs ta;
    ta.src[0] = a1_wq; ta.dst[0] = wT_a1qv;               ta.R[0] = 512;  ta.C[0] = 512;
    ta.src[1] = a1_wv; ta.dst[1] = wT_a1qv + 512 * 512;   ta.R[1] = 512;  ta.C[1] = 512;
    ta.src[2] = a2_wq; ta.dst[2] = wT_a2qv;               ta.R[2] = 512;  ta.C[2] = 512;
    ta.src[3] = a2_wv; ta.dst[3] = wT_a2qv + 512 * 512;   ta.R[3] = 512;  ta.C[3] = 512;
    ta.src[4] = a1_wo; ta.dst[4] = wT_a1o;                ta.R[4] = 512;  ta.C[4] = 512;
    ta.src[5] = a2_wo; ta.dst[5] = wT_a2o;                ta.R[5] = 512;  ta.C[5] = 512;
    ta.src[6] = ff_w1; ta.dst[6] = wT_ff1;                ta.R[6] = 512;  ta.C[6] = 4096;
    ta.src[7] = ff_w2; ta.dst[7] = wT_ff2;                ta.R[7] = 2048; ta.C[7] = 512;
    ta.start[0] = 0;
    for (int s = 0; s < 8; s++)
        ta.start[s + 1] = ta.start[s] + (ta.C[s] >> 5) * (ta.R[s] >> 5);
    transpose_multi<<<ta.start[8], 256, 0, stream>>>(ta);

    // === attention 1 (self) ===
    ln_kernel<<<2048, 256, 0, stream>>>(x, sa_w, sa_b, xn);
    gemm_qv<<<dim3(64, 8), 256, 0, stream>>>(xn, wT_a1qv, a1_bq, a1_bv, qbuf, vtp, aab, 512);
    attn_mfma<<<512, 256, 0, stream>>>(qbuf, vtp, aab, attn_o);
    gemm_rect<2><<<dim3(64, 8), 256, 0, stream>>>(attn_o, wT_a1o, a1_bo, x, x_res, 8192, 512, 512);

    // === attention 2 ("cross", k=q, v from x) ===
    ln_kernel<<<2048, 256, 0, stream>>>(x_res, ca_w, ca_b, xn);
    gemm_qv<<<dim3(64, 8), 256, 0, stream>>>(xn, wT_a2qv, a2_bq, a2_bv, qbuf, vtp, aab, 512);
    attn_mfma<<<512, 256, 0, stream>>>(qbuf, vtp, aab, attn_o);
    gemm_rect<2><<<dim3(64, 8), 256, 0, stream>>>(attn_o, wT_a2o, a2_bo, x_res, x_res, 8192, 512, 512);

    // === GEGLU FFN (geglu fused into ff1) ===
    ln_kernel<<<2048, 256, 0, stream>>>(x_res, ffn_w, ffn_b, xn);
    gemm_ff1<<<dim3(64, 32), 256, 0, stream>>>(xn, wT_ff1, ff_b1, gbuf, 512);
    gemm_rect<2><<<dim3(64, 8), 256, 0, stream>>>(gbuf, wT_ff2, ff_b2, x_res, (float*)d_out, 8192, 512, 2048);
}

// Round 12
// 379.247 us; speedup vs baseline: 1.0227x; 1.0227x over previous
//
#include <hip/hip_runtime.h>
#include <hip/hip_bf16.h>

// ---------------------------------------------------------------------------
// BasicTransformerBlock (l2-attention x2 + GEGLU FFN), MI355X gfx950
// Round 22: keep round-21 attn (60.1us, counters improved). New: ff2 (K=2048)
// moves to BK=64 gemm_rect64 (6-load staging, vmcnt(6), 16 MFMA/step,
// barriers 128->64, LDS 48KB = still 2 blocks/CU). Out-projections stay BK=32.
// ---------------------------------------------------------------------------

typedef short bf16x8 __attribute__((ext_vector_type(8)));
typedef float f32x4 __attribute__((ext_vector_type(4)));
typedef unsigned short u16;
typedef unsigned int u32;

__device__ __forceinline__ float bf2f(u16 u) {
    return __uint_as_float(((u32)u) << 16);
}
__device__ __forceinline__ u16 f2bf(float f) {
    u32 u = __float_as_uint(f);
    u32 rb = ((u >> 16) & 1u) + 0x7fffu;   // round-to-nearest-even
    return (u16)((u + rb) >> 16);
}
// tanh-form gelu: x * sigmoid(1.59577(x + 0.044715 x^3)); |err| <~1e-3.
__device__ __forceinline__ float gelu_fast(float x) {
    float y = 1.5957691216f * (x + 0.044715f * x * x * x);
    return x / (1.f + __expf(-y));
}
__device__ __forceinline__ void gl2lds16(const u16* g, u16* l) {
    __builtin_amdgcn_global_load_lds(
        (const __attribute__((address_space(1))) void*)(unsigned long long)(uintptr_t)g,
        (__attribute__((address_space(3))) void*)(unsigned long long)(uintptr_t)l,
        16, 0, 0);
}

// ---------------------------------------------------------------------------
// Merged weight transpose: 8 segments of fp32 [R][C] -> bf16 [C][R].
struct TArgs {
    const float* src[8];
    u16* dst[8];
    int R[8], C[8];
    int start[9];
};
__global__ __launch_bounds__(256) void transpose_multi(TArgs a) {
    __shared__ float tile[32][33];
    int bid = blockIdx.x;
    int s = 0;
    while (bid >= a.start[s + 1]) s++;
    int local = bid - a.start[s];
    int R = a.R[s], C = a.C[s];
    int tx = C >> 5;
    int bx = local % tx, by = local / tx;
    const float* in = a.src[s];
    u16* out = a.dst[s];
    int t = threadIdx.x;
    int c = t & 31, r0 = (t >> 5) * 4;
#pragma unroll
    for (int i = 0; i < 4; i++)
        tile[r0 + i][c] = in[(size_t)(by * 32 + r0 + i) * C + bx * 32 + c];
    __syncthreads();
#pragma unroll
    for (int i = 0; i < 4; i++)
        out[(size_t)(bx * 32 + r0 + i) * R + by * 32 + c] = f2bf(tile[c][r0 + i]);
}

// ---------------------------------------------------------------------------
// LayerNorm: x fp32 [rows][512] -> out bf16. One WAVE per row (4 rows/block),
// 8 elems/lane, shfl-only reduction (no LDS, no barrier). Grid 2048.
__global__ __launch_bounds__(256) void ln_kernel(const float* __restrict__ x,
                                                 const float* __restrict__ w,
                                                 const float* __restrict__ b,
                                                 u16* __restrict__ out) {
    int t = threadIdx.x;
    int wave = t >> 6, lane = t & 63;
    int row = blockIdx.x * 4 + wave;
    const float* xr = x + (size_t)row * 512 + lane * 8;
    float4 v0 = *(const float4*)xr;
    float4 v1 = *(const float4*)(xr + 4);
    float s1 = (v0.x + v0.y) + (v0.z + v0.w) + (v1.x + v1.y) + (v1.z + v1.w);
    float s2 = (v0.x * v0.x + v0.y * v0.y) + (v0.z * v0.z + v0.w * v0.w) +
               (v1.x * v1.x + v1.y * v1.y) + (v1.z * v1.z + v1.w * v1.w);
#pragma unroll
    for (int m = 1; m < 64; m <<= 1) {
        s1 += __shfl_xor(s1, m);
        s2 += __shfl_xor(s2, m);
    }
    float mu = s1 * (1.f / 512.f);
    float var = s2 * (1.f / 512.f) - mu * mu;
    float rs = rsqrtf(var + 1e-5f);
    const float* wp = w + lane * 8;
    const float* bp = b + lane * 8;
    float4 w0 = *(const float4*)wp;
    float4 w1 = *(const float4*)(wp + 4);
    float4 b0 = *(const float4*)bp;
    float4 b1 = *(const float4*)(bp + 4);
    u16 r[8];
    r[0] = f2bf((v0.x - mu) * rs * w0.x + b0.x);
    r[1] = f2bf((v0.y - mu) * rs * w0.y + b0.y);
    r[2] = f2bf((v0.z - mu) * rs * w0.z + b0.z);
    r[3] = f2bf((v0.w - mu) * rs * w0.w + b0.w);
    r[4] = f2bf((v1.x - mu) * rs * w1.x + b1.x);
    r[5] = f2bf((v1.y - mu) * rs * w1.y + b1.y);
    r[6] = f2bf((v1.z - mu) * rs * w1.z + b1.z);
    r[7] = f2bf((v1.w - mu) * rs * w1.w + b1.w);
    *(uint4*)(out + (size_t)row * 512 + lane * 8) = *(uint4*)r;
}

// ---------------------------------------------------------------------------
// ff1+GEGLU fused rect GEMM: A [8192][512] bf16, BT = ff1^T [4096][512].
// Epilogue: g = a * gelu(gate) -> gbuf [8192][2048] bf16.
__global__ __launch_bounds__(256) void gemm_ff1(const u16* __restrict__ A,
                                                const u16* __restrict__ BT,
                                                const float* __restrict__ bias,
                                                u16* __restrict__ gout,
                                                int K) {
    __shared__ u16 As[2][128 * 32];
    __shared__ u16 Bs[2][128 * 32];   // rows 0-63 = a-half, 64-127 = gate-half
    int t = threadIdx.x;
    int wave = t >> 6, lane = t & 63, quad = lane >> 4, l16 = lane & 15;
    int m0 = blockIdx.x * 128, n0 = blockIdx.y * 64;
    f32x4 aacc[2][4], gacc[2][4];
#pragma unroll
    for (int i = 0; i < 2; i++)
#pragma unroll
        for (int j = 0; j < 4; j++) {
            aacc[i][j] = (f32x4){0.f, 0.f, 0.f, 0.f};
            gacc[i][j] = (f32x4){0.f, 0.f, 0.f, 0.f};
        }
    const u16* Ag = A + (size_t)(m0 + wave * 32 + (lane >> 2)) * K + (lane & 3) * 8;
    int brow = (wave < 2) ? (n0 + wave * 32) : (2048 + n0 + (wave - 2) * 32);
    const u16* Bg = BT + (size_t)(brow + (lane >> 2)) * K + (lane & 3) * 8;
    int lo = wave * 32 * 32;
    const size_t rstep = (size_t)16 * K;
    gl2lds16(Ag, &As[0][lo]);
    gl2lds16(Ag + rstep, &As[0][lo + 16 * 32]);
    gl2lds16(Bg, &Bs[0][lo]);
    gl2lds16(Bg + rstep, &Bs[0][lo + 16 * 32]);
    int buf = 0;
    for (int k0 = 0; k0 < K; k0 += 32, buf ^= 1) {
        int kn = (k0 + 32 < K) ? (k0 + 32) : k0;
        int nb = buf ^ 1;
        asm volatile("s_waitcnt lgkmcnt(0)\n\ts_barrier" ::: "memory");
        gl2lds16(Ag + kn, &As[nb][lo]);
        gl2lds16(Ag + kn + rstep, &As[nb][lo + 16 * 32]);
        gl2lds16(Bg + kn, &Bs[nb][lo]);
        gl2lds16(Bg + kn + rstep, &Bs[nb][lo + 16 * 32]);
        asm volatile("s_waitcnt vmcnt(4)\n\ts_barrier" ::: "memory");
        bf16x8 a[2];
#pragma unroll
        for (int i = 0; i < 2; i++)
            a[i] = *(const bf16x8*)&As[buf][(wave * 32 + i * 16 + l16) * 32 + quad * 8];
#pragma unroll
        for (int j = 0; j < 4; j++) {
            bf16x8 ba = *(const bf16x8*)&Bs[buf][(j * 16 + l16) * 32 + quad * 8];
            bf16x8 bg = *(const bf16x8*)&Bs[buf][(64 + j * 16 + l16) * 32 + quad * 8];
#pragma unroll
            for (int i = 0; i < 2; i++) {
                aacc[i][j] = __builtin_amdgcn_mfma_f32_16x16x32_bf16(a[i], ba, aacc[i][j], 0, 0, 0);
                gacc[i][j] = __builtin_amdgcn_mfma_f32_16x16x32_bf16(a[i], bg, gacc[i][j], 0, 0, 0);
            }
        }
    }
    asm volatile("s_waitcnt vmcnt(0)" ::: "memory");   // drain DMA before endpgm
    int row_base = m0 + wave * 32 + quad * 4;
#pragma unroll
    for (int j = 0; j < 4; j++) {
        int col = n0 + j * 16 + l16;
        float ba = bias[col];
        float bg = bias[2048 + col];
#pragma unroll
        for (int i = 0; i < 2; i++) {
#pragma unroll
            for (int r = 0; r < 4; r++) {
                int row = row_base + i * 16 + r;
                float av = aacc[i][j][r] + ba;
                float gv = gacc[i][j][r] + bg;
                gout[(size_t)row * 2048 + col] = f2bf(av * gelu_fast(gv));
            }
        }
    }
}

// ---------------------------------------------------------------------------
// q/v projection GEMM, 128x128 tile: A [8192][512], BT [1024][512].
// Block is entirely q (n0<512) or entirely v. Fused AA per j-half.
__global__ __launch_bounds__(256) void gemm_qv(const u16* __restrict__ A,
                                               const u16* __restrict__ BT,
                                               const float* __restrict__ bias,
                                               const float* __restrict__ bias2,
                                               u16* __restrict__ outb,
                                               u16* __restrict__ outb2,
                                               float* __restrict__ aa,
                                               int K) {
    __shared__ u16 As[2][128 * 32];
    __shared__ u16 Bs[2][128 * 32];
    int t = threadIdx.x;
    int wave = t >> 6, lane = t & 63, quad = lane >> 4, l16 = lane & 15;
    int m0 = blockIdx.x * 128, n0 = blockIdx.y * 128;
    f32x4 acc[2][8];
#pragma unroll
    for (int i = 0; i < 2; i++)
#pragma unroll
        for (int j = 0; j < 8; j++) acc[i][j] = (f32x4){0.f, 0.f, 0.f, 0.f};
    const u16* Ag = A + (size_t)(m0 + wave * 32 + (lane >> 2)) * K + (lane & 3) * 8;
    const u16* Bg = BT + (size_t)(n0 + wave * 32 + (lane >> 2)) * K + (lane & 3) * 8;
    int lo = wave * 32 * 32;
    const size_t rstep = (size_t)16 * K;
    gl2lds16(Ag, &As[0][lo]);
    gl2lds16(Ag + rstep, &As[0][lo + 16 * 32]);
    gl2lds16(Bg, &Bs[0][lo]);
    gl2lds16(Bg + rstep, &Bs[0][lo + 16 * 32]);
    int buf = 0;
    for (int k0 = 0; k0 < K; k0 += 32, buf ^= 1) {
        int kn = (k0 + 32 < K) ? (k0 + 32) : k0;
        int nb = buf ^ 1;
        asm volatile("s_waitcnt lgkmcnt(0)\n\ts_barrier" ::: "memory");
        gl2lds16(Ag + kn, &As[nb][lo]);
        gl2lds16(Ag + kn + rstep, &As[nb][lo + 16 * 32]);
        gl2lds16(Bg + kn, &Bs[nb][lo]);
        gl2lds16(Bg + kn + rstep, &Bs[nb][lo + 16 * 32]);
        asm volatile("s_waitcnt vmcnt(4)\n\ts_barrier" ::: "memory");
        bf16x8 a[2];
#pragma unroll
        for (int i = 0; i < 2; i++)
            a[i] = *(const bf16x8*)&As[buf][(wave * 32 + i * 16 + l16) * 32 + quad * 8];
#pragma unroll
        for (int j = 0; j < 8; j++) {
            bf16x8 b = *(const bf16x8*)&Bs[buf][(j * 16 + l16) * 32 + quad * 8];
#pragma unroll
            for (int i = 0; i < 2; i++)
                acc[i][j] = __builtin_amdgcn_mfma_f32_16x16x32_bf16(a[i], b, acc[i][j], 0, 0, 0);
        }
    }
    asm volatile("s_waitcnt vmcnt(0)" ::: "memory");   // drain DMA before endpgm
    int row_base = m0 + wave * 32 + quad * 4;
    bool isq = (n0 < 512);
    float ssq[2][2][4];   // [jh][i][r]
#pragma unroll
    for (int jh = 0; jh < 2; jh++)
#pragma unroll
        for (int i = 0; i < 2; i++)
#pragma unroll
            for (int r = 0; r < 4; r++) ssq[jh][i][r] = 0.f;
#pragma unroll
    for (int j = 0; j < 8; j++) {
        int col = n0 + j * 16 + l16;
        float bv = isq ? bias[col] : bias2[col - 512];
        int jh = j >> 2;
#pragma unroll
        for (int i = 0; i < 2; i++) {
            int rowA = row_base + i * 16;
            if (isq) {
                int hh = col >> 6, d = col & 63;
#pragma unroll
                for (int r = 0; r < 4; r++) {
                    int row = rowA + r;
                    float v = acc[i][j][r] + bv;
                    ssq[jh][i][r] += v * v;
                    outb[((size_t)((row >> 11) * 8 + hh) * 2048 + (row & 2047)) * 64 + d] = f2bf(v);
                }
            } else {
                int c2 = col - 512;
                int hh = c2 >> 6, d = c2 & 63;
                int n = rowA & 2047;
                int a4 = (n >> 2) & 7;
                int ncol = (n & ~31) + ((a4 & 3) << 3) + ((a4 >> 2) << 2);
                u32 plo = (u32)f2bf(acc[i][j][0] + bv) | ((u32)f2bf(acc[i][j][1] + bv) << 16);
                u32 phi = (u32)f2bf(acc[i][j][2] + bv) | ((u32)f2bf(acc[i][j][3] + bv) << 16);
                uint2 pk; pk.x = plo; pk.y = phi;
                *(uint2*)&outb2[((size_t)((rowA >> 11) * 8 + hh) * 64 + d) * 2048 + ncol] = pk;
            }
        }
    }
    // fused AA (aa = 0.125*log2e*||q||^2), one head per j-half
    if (isq) {
#pragma unroll
        for (int jh = 0; jh < 2; jh++) {
            int hh = (n0 >> 6) + jh;
#pragma unroll
            for (int i = 0; i < 2; i++) {
#pragma unroll
                for (int r = 0; r < 4; r++) {
                    float s = ssq[jh][i][r];
                    s += __shfl_xor(s, 1); s += __shfl_xor(s, 2);
                    s += __shfl_xor(s, 4); s += __shfl_xor(s, 8);
                    if (l16 == 0) {
                        int row = row_base + i * 16 + r;
                        aa[(size_t)((row >> 11) * 8 + hh) * 2048 + (row & 2047)] = s * 0.18033688f;
                    }
                }
            }
        }
    }
}

// ---------------------------------------------------------------------------
// Rect 128x64 MFMA GEMM BK=32 (double-buffered, vmcnt(3)): out = acc+bias+res.
template <int MODE>
__global__ __launch_bounds__(256) void gemm_rect(const u16* __restrict__ A,
                                                 const u16* __restrict__ BT,
                                                 const float* __restrict__ bias,
                                                 const float* __restrict__ res,
                                                 float* __restrict__ outf,
                                                 int M, int N, int K) {
    __shared__ u16 As[2][128 * 32];
    __shared__ u16 Bs[2][64 * 32];
    int t = threadIdx.x;
    int wave = t >> 6, lane = t & 63, quad = lane >> 4, l16 = lane & 15;
    int m0 = blockIdx.x * 128, n0 = blockIdx.y * 64;
    f32x4 acc[2][4];
#pragma unroll
    for (int i = 0; i < 2; i++)
#pragma unroll
        for (int j = 0; j < 4; j++) acc[i][j] = (f32x4){0.f, 0.f, 0.f, 0.f};
    const u16* Ag = A + (size_t)(m0 + wave * 32 + (lane >> 2)) * K + (lane & 3) * 8;
    const u16* Bg = BT + (size_t)(n0 + wave * 16 + (lane >> 2)) * K + (lane & 3) * 8;
    int loA = wave * 32 * 32;
    int loB = wave * 16 * 32;
    const size_t rstep = (size_t)16 * K;
    gl2lds16(Ag, &As[0][loA]);
    gl2lds16(Ag + rstep, &As[0][loA + 16 * 32]);
    gl2lds16(Bg, &Bs[0][loB]);
    int buf = 0;
    for (int k0 = 0; k0 < K; k0 += 32, buf ^= 1) {
        int kn = (k0 + 32 < K) ? (k0 + 32) : k0;
        int nb = buf ^ 1;
        asm volatile("s_waitcnt lgkmcnt(0)\n\ts_barrier" ::: "memory");
        gl2lds16(Ag + kn, &As[nb][loA]);
        gl2lds16(Ag + kn + rstep, &As[nb][loA + 16 * 32]);
        gl2lds16(Bg + kn, &Bs[nb][loB]);
        asm volatile("s_waitcnt vmcnt(3)\n\ts_barrier" ::: "memory");
        bf16x8 a[2], b[4];
#pragma unroll
        for (int i = 0; i < 2; i++)
            a[i] = *(const bf16x8*)&As[buf][(wave * 32 + i * 16 + l16) * 32 + quad * 8];
#pragma unroll
        for (int j = 0; j < 4; j++)
            b[j] = *(const bf16x8*)&Bs[buf][(j * 16 + l16) * 32 + quad * 8];
#pragma unroll
        for (int i = 0; i < 2; i++)
#pragma unroll
            for (int j = 0; j < 4; j++)
                acc[i][j] = __builtin_amdgcn_mfma_f32_16x16x32_bf16(a[i], b[j], acc[i][j], 0, 0, 0);
    }
    asm volatile("s_waitcnt vmcnt(0)" ::: "memory");   // drain DMA before endpgm
    int row_base = m0 + wave * 32 + quad * 4;
#pragma unroll
    for (int j = 0; j < 4; j++) {
        int col = n0 + j * 16 + l16;
        float bv = bias[col];
#pragma unroll
        for (int i = 0; i < 2; i++) {
            int rowA = row_base + i * 16;
#pragma unroll
            for (int r = 0; r < 4; r++) {
                size_t idx = (size_t)(rowA + r) * N + col;
                outf[idx] = acc[i][j][r] + bv + res[idx];
            }
        }
    }
}

// ---------------------------------------------------------------------------
// Rect 128x64 MFMA GEMM BK=64 (for large K): 6-load staging, vmcnt(6),
// 16 MFMA per K-step over two k-halves, half the barriers of BK=32.
// LDS 48KB -> 2 blocks/CU. fp32 out = acc + bias + res.
__global__ __launch_bounds__(256) void gemm_rect64(const u16* __restrict__ A,
                                                   const u16* __restrict__ BT,
                                                   const float* __restrict__ bias,
                                                   const float* __restrict__ res,
                                                   float* __restrict__ outf,
                                                   int N, int K) {
    __shared__ u16 As[2][128 * 64];
    __shared__ u16 Bs[2][64 * 64];
    int t = threadIdx.x;
    int wave = t >> 6, lane = t & 63, quad = lane >> 4, l16 = lane & 15;
    int m0 = blockIdx.x * 128, n0 = blockIdx.y * 64;
    f32x4 acc[2][4];
#pragma unroll
    for (int i = 0; i < 2; i++)
#pragma unroll
        for (int j = 0; j < 4; j++) acc[i][j] = (f32x4){0.f, 0.f, 0.f, 0.f};
    // staging: thread covers row (chunk*32 + wave*8 + (lane>>3)), col (lane&7)*8;
    // per-wave LDS dest = chunk*32*64 + wave*512 (+ lane*8 implicit).
    const u16* Ag = A + (size_t)(m0 + wave * 8 + (lane >> 3)) * K + (lane & 7) * 8;
    const u16* Bg = BT + (size_t)(n0 + wave * 8 + (lane >> 3)) * K + (lane & 7) * 8;
    int lo = wave * 512;
    const size_t rstep = (size_t)32 * K;
#pragma unroll
    for (int cc = 0; cc < 4; cc++)
        gl2lds16(Ag + cc * rstep, &As[0][cc * 2048 + lo]);
#pragma unroll
    for (int cc = 0; cc < 2; cc++)
        gl2lds16(Bg + cc * rstep, &Bs[0][cc * 2048 + lo]);
    int buf = 0;
    for (int k0 = 0; k0 < K; k0 += 64, buf ^= 1) {
        int kn = (k0 + 64 < K) ? (k0 + 64) : k0;
        int nb = buf ^ 1;
        asm volatile("s_waitcnt lgkmcnt(0)\n\ts_barrier" ::: "memory");
#pragma unroll
        for (int cc = 0; cc < 4; cc++)
            gl2lds16(Ag + kn + cc * rstep, &As[nb][cc * 2048 + lo]);
#pragma unroll
        for (int cc = 0; cc < 2; cc++)
            gl2lds16(Bg + kn + cc * rstep, &Bs[nb][cc * 2048 + lo]);
        asm volatile("s_waitcnt vmcnt(6)\n\ts_barrier" ::: "memory");
#pragma unroll
        for (int kk = 0; kk < 2; kk++) {
            bf16x8 a[2], b[4];
#pragma unroll
            for (int i = 0; i < 2; i++)
                a[i] = *(const bf16x8*)&As[buf][(wave * 32 + i * 16 + l16) * 64 + kk * 32 + quad * 8];
#pragma unroll
            for (int j = 0; j < 4; j++)
                b[j] = *(const bf16x8*)&Bs[buf][(j * 16 + l16) * 64 + kk * 32 + quad * 8];
#pragma unroll
            for (int i = 0; i < 2; i++)
#pragma unroll
                for (int j = 0; j < 4; j++)
                    acc[i][j] = __builtin_amdgcn_mfma_f32_16x16x32_bf16(a[i], b[j], acc[i][j], 0, 0, 0);
        }
    }
    asm volatile("s_waitcnt vmcnt(0)" ::: "memory");   // drain DMA before endpgm
    int row_base = m0 + wave * 32 + quad * 4;
#pragma unroll
    for (int j = 0; j < 4; j++) {
        int col = n0 + j * 16 + l16;
        float bv = bias[col];
#pragma unroll
        for (int i = 0; i < 2; i++) {
            int rowA = row_base + i * 16;
#pragma unroll
            for (int r = 0; r < 4; r++) {
                size_t idx = (size_t)(rowA + r) * N + col;
                outf[idx] = acc[i][j][r] + bv + res[idx];
            }
        }
    }
}

// ---------------------------------------------------------------------------
// MFMA flash L2-attention, S^T formulation, 2 i-subtiles/wave, swizzled LDS,
// 128-KV tiles, ci-free exp2 softmax, software-pipelined c-loop (QK(c+1)
// under exp/PV(c)), lr via MFMA row-sum (P @ ones -> sacc).
// Grid 512: bh = bid & 31 (xcd = bh%8), itile = bid >> 5 (16 x 128 q-rows).
__global__ __launch_bounds__(256) void attn_mfma(const u16* __restrict__ qbuf,
                                                 const u16* __restrict__ vtp,
                                                 const float* __restrict__ aas,
                                                 u16* __restrict__ out) {
    // per buffer: [0..8191] = Q-tile 128x64 (swz), [8192..16383] = V-tile 64x128 (swz)
    __shared__ u16 L[2][16384];
    int bid = blockIdx.x;
    int bh = bid & 31;
    int itile = bid >> 5;
    const u16* qb = qbuf + (size_t)bh * 2048 * 64;
    const u16* vtb = vtp + (size_t)bh * 64 * 2048;
    const float* aab = aas + (size_t)bh * 2048;
    int t = threadIdx.x;
    int wave = t >> 6, lane = t & 63, quad = lane >> 4, l16 = lane & 15;
    int sw7 = l16 & 7;
    int ibase = itile * 128 + wave * 32;

    bf16x8 qf[2][2];
    f32x4 O[2][4];
    f32x4 sacc[2];
#pragma unroll
    for (int st = 0; st < 2; st++) {
        const u16* qr = qb + (size_t)(ibase + st * 16 + l16) * 64;
        qf[st][0] = *(const bf16x8*)(qr + quad * 8);
        qf[st][1] = *(const bf16x8*)(qr + 32 + quad * 8);
        sacc[st] = (f32x4){0.f, 0.f, 0.f, 0.f};
#pragma unroll
        for (int nt = 0; nt < 4; nt++) O[st][nt] = (f32x4){0.f, 0.f, 0.f, 0.f};
    }
    bf16x8 vones;
    {
        u32* vo = (u32*)&vones;
        vo[0] = vo[1] = vo[2] = vo[3] = 0x3F803F80u;   // 8 x bf16(1.0)
    }

    // staging geometry: 4 Q slots (128 rows x 8 slots) + 4 V slots (64 rows x 16 slots)
    int qrow[4], qcs[4], qwof[4], vrow[4], vsl[4], vwof[4];
#pragma unroll
    for (int k = 0; k < 4; k++) {
        int s = t + k * 256;
        qrow[k] = s >> 3; qcs[k] = s & 7;
        qwof[k] = qrow[k] * 64 + 8 * (qcs[k] ^ (qrow[k] & 7));
        vrow[k] = s >> 4; vsl[k] = s & 15;
        vwof[k] = 8192 + vrow[k] * 128 + 8 * ((vsl[k] & 8) | ((vsl[k] & 7) ^ (vrow[k] & 7)));
    }
    // prologue: tile j0 = 0 into buf 0
#pragma unroll
    for (int k = 0; k < 4; k++) {
        *(uint4*)&L[0][qwof[k]] = *(const uint4*)(qb + (size_t)qrow[k] * 64 + qcs[k] * 8);
        *(uint4*)&L[0][vwof[k]] = *(const uint4*)(vtb + (size_t)vrow[k] * 2048 + vsl[k] * 8);
    }
    __syncthreads();

    const float C0 = 0.36067376f;   // 0.25 * log2(e)
    for (int it = 0; it < 16; ++it) {
        int cur = it & 1;
        int j0 = it << 7;
        uint4 pq[4], pv[4];
        bool more = (it + 1 < 16);
        if (more) {
            int j0n = j0 + 128;
#pragma unroll
            for (int k = 0; k < 4; k++) {
                pq[k] = *(const uint4*)(qb + (size_t)(j0n + qrow[k]) * 64 + qcs[k] * 8);
                pv[k] = *(const uint4*)(vtb + (size_t)vrow[k] * 2048 + j0n + vsl[k] * 8);
            }
        }
        const u16* Q = &L[cur][0];
        const u16* V = &L[cur][8192];

        auto QK = [&](int c, f32x4 s0o[2], f32x4 s1o[2]) {
            int r10 = c * 32 + l16, r20 = c * 32 + 16 + l16;
            bf16x8 a10 = *(const bf16x8*)&Q[r10 * 64 + 8 * (quad ^ sw7)];
            bf16x8 a11 = *(const bf16x8*)&Q[r10 * 64 + 8 * ((4 + quad) ^ sw7)];
            bf16x8 a20 = *(const bf16x8*)&Q[r20 * 64 + 8 * (quad ^ sw7)];
            bf16x8 a21 = *(const bf16x8*)&Q[r20 * 64 + 8 * ((4 + quad) ^ sw7)];
            __builtin_amdgcn_s_setprio(1);
#pragma unroll
            for (int st = 0; st < 2; st++) {
                f32x4 z = {0.f, 0.f, 0.f, 0.f};
                s0o[st] = __builtin_amdgcn_mfma_f32_16x16x32_bf16(a10, qf[st][0], z, 0, 0, 0);
                s0o[st] = __builtin_amdgcn_mfma_f32_16x16x32_bf16(a11, qf[st][1], s0o[st], 0, 0, 0);
                s1o[st] = __builtin_amdgcn_mfma_f32_16x16x32_bf16(a20, qf[st][0], z, 0, 0, 0);
                s1o[st] = __builtin_amdgcn_mfma_f32_16x16x32_bf16(a21, qf[st][1], s1o[st], 0, 0, 0);
            }
            __builtin_amdgcn_s_setprio(0);
        };

        f32x4 sc0[2], sc1[2], sn0[2], sn1[2];
        QK(0, sc0, sc1);
#pragma unroll
        for (int c = 0; c < 4; c++) {
            if (c < 3) QK(c + 1, sn0, sn1);   // issue next QK under this c's exp/PV
            float4 aav0 = *(const float4*)(aab + j0 + c * 32 + quad * 4);
            float4 aav1 = *(const float4*)(aab + j0 + c * 32 + 16 + quad * 4);
            bf16x8 pa[2];
#pragma unroll
            for (int st = 0; st < 2; st++) {
                float p0 = __builtin_amdgcn_exp2f(fmaf(sc0[st][0], C0, -aav0.x));
                float p1 = __builtin_amdgcn_exp2f(fmaf(sc0[st][1], C0, -aav0.y));
                float p2 = __builtin_amdgcn_exp2f(fmaf(sc0[st][2], C0, -aav0.z));
                float p3 = __builtin_amdgcn_exp2f(fmaf(sc0[st][3], C0, -aav0.w));
                float p4 = __builtin_amdgcn_exp2f(fmaf(sc1[st][0], C0, -aav1.x));
                float p5 = __builtin_amdgcn_exp2f(fmaf(sc1[st][1], C0, -aav1.y));
                float p6 = __builtin_amdgcn_exp2f(fmaf(sc1[st][2], C0, -aav1.z));
                float p7 = __builtin_amdgcn_exp2f(fmaf(sc1[st][3], C0, -aav1.w));
                u32* pu = (u32*)&pa[st];
                pu[0] = __builtin_amdgcn_perm(__float_as_uint(p1), __float_as_uint(p0), 0x07060302u);
                pu[1] = __builtin_amdgcn_perm(__float_as_uint(p3), __float_as_uint(p2), 0x07060302u);
                pu[2] = __builtin_amdgcn_perm(__float_as_uint(p5), __float_as_uint(p4), 0x07060302u);
                pu[3] = __builtin_amdgcn_perm(__float_as_uint(p7), __float_as_uint(p6), 0x07060302u);
            }
            __builtin_amdgcn_s_setprio(1);
#pragma unroll
            for (int nt = 0; nt < 4; nt++) {
                int sl = c * 4 + quad;
                bf16x8 vf = *(const bf16x8*)&V[(nt * 16 + l16) * 128 + 8 * ((sl & 8) | ((sl & 7) ^ sw7))];
                O[0][nt] = __builtin_amdgcn_mfma_f32_16x16x32_bf16(pa[0], vf, O[0][nt], 0, 0, 0);
                O[1][nt] = __builtin_amdgcn_mfma_f32_16x16x32_bf16(pa[1], vf, O[1][nt], 0, 0, 0);
            }
            // lr via MFMA row-sum: D[i][n] = sum_j P[i][j] (denominator, bf16-P
            // consistent with the PV numerator)
            sacc[0] = __builtin_amdgcn_mfma_f32_16x16x32_bf16(pa[0], vones, sacc[0], 0, 0, 0);
            sacc[1] = __builtin_amdgcn_mfma_f32_16x16x32_bf16(pa[1], vones, sacc[1], 0, 0, 0);
            __builtin_amdgcn_s_setprio(0);
#pragma unroll
            for (int st = 0; st < 2; st++) { sc0[st] = sn0[st]; sc1[st] = sn1[st]; }
        }
        if (more) {
            u16* D = &L[cur ^ 1][0];
#pragma unroll
            for (int k = 0; k < 4; k++) {
                *(uint4*)&D[qwof[k]] = pq[k];
                *(uint4*)&D[vwof[k]] = pv[k];
            }
        }
        __syncthreads();
    }

    int b = bh >> 3, h = bh & 7;
#pragma unroll
    for (int st = 0; st < 2; st++) {
#pragma unroll
        for (int r = 0; r < 4; r++) {
            float invr = 1.f / sacc[st][r];
            size_t row = (size_t)(b * 2048 + ibase + st * 16 + quad * 4 + r);
            u16* o = out + row * 512 + h * 64 + l16;
            o[0]  = f2bf(O[st][0][r] * invr);
            o[16] = f2bf(O[st][1][r] * invr);
            o[32] = f2bf(O[st][2][r] * invr);
            o[48] = f2bf(O[st][3][r] * invr);
        }
    }
}

// ---------------------------------------------------------------------------
extern "C" void kernel_launch(void* const* d_in, const int* in_sizes, int n_in,
                              void* d_out, int out_size, void* d_ws, size_t ws_size,
                              hipStream_t stream) {
    const float* x      = (const float*)d_in[0];
    const float* sa_w   = (const float*)d_in[1];
    const float* sa_b   = (const float*)d_in[2];
    const float* ca_w   = (const float*)d_in[3];
    const float* ca_b   = (const float*)d_in[4];
    const float* ffn_w  = (const float*)d_in[5];
    const float* ffn_b  = (const float*)d_in[6];
    const float* a1_wq  = (const float*)d_in[7];
    const float* a1_bq  = (const float*)d_in[8];
    const float* a1_wv  = (const float*)d_in[9];
    const float* a1_bv  = (const float*)d_in[10];
    const float* a1_wo  = (const float*)d_in[11];
    const float* a1_bo  = (const float*)d_in[12];
    const float* a2_wq  = (const float*)d_in[13];
    const float* a2_bq  = (const float*)d_in[14];
    const float* a2_wv  = (const float*)d_in[15];
    const float* a2_bv  = (const float*)d_in[16];
    const float* a2_wo  = (const float*)d_in[17];
    const float* a2_bo  = (const float*)d_in[18];
    const float* ff_w1  = (const float*)d_in[19];
    const float* ff_b1  = (const float*)d_in[20];
    const float* ff_w2  = (const float*)d_in[21];
    const float* ff_b2  = (const float*)d_in[22];

    char* ws = (char*)d_ws;
    const size_t MB = 1ull << 20;
    float* x_res   = (float*)(ws);              // 16 MB fp32 residual stream
    u16* xn        = (u16*)(ws + 16 * MB);      // 8 MB normed activations (bf16)
    u16* wT_a1qv   = (u16*)(ws + 24 * MB);      // 1 MB [1024][512] (wq^T | wv^T)
    u16* wT_a2qv   = (u16*)(ws + 25 * MB);      // 1 MB
    u16* wT_a1o    = (u16*)(ws + 26 * MB);      // 0.5 MB
    u16* wT_a2o    = (u16*)(ws + 26 * MB + 512 * 1024);
    u16* wT_ff1    = (u16*)(ws + 27 * MB);      // 4 MB [4096][512]
    u16* wT_ff2    = (u16*)(ws + 31 * MB);      // 2 MB [512][2048]
    u16* qbuf      = (u16*)(ws + 34 * MB);      // 8 MB [bh][2048][64]
    u16* vtp       = (u16*)(ws + 42 * MB);      // 8 MB [bh][64][2048] (j-permuted)
    float* aab     = (float*)(ws + 50 * MB);    // 256 KB (0.125*log2e*||q||^2)
    u16* attn_o    = (u16*)(ws + 51 * MB);      // 8 MB bf16 [8192][512]
    u16* gbuf      = (u16*)(ws + 60 * MB);      // 32 MB [8192][2048] bf16

    (void)in_sizes; (void)n_in; (void)out_size; (void)ws_size;

    // merged weight transposes (fp32 -> bf16 [N][K]); q|v concatenated
    TArgs ta;
    ta.src[0] = a1_wq; ta.dst[0] = wT_a1qv;               ta.R[0] = 512;  ta.C[0] = 512;
    ta.src[1] = a1_wv; ta.dst[1] = wT_a1qv + 512 * 512;   ta.R[1] = 512;  ta.C[1] = 512;
    ta.src[2] = a2_wq; ta.dst[2] = wT_a2qv;               ta.R[2] = 512;  ta.C[2] = 512;
    ta.src[3] = a2_wv; ta.dst[3] = wT_a2qv + 512 * 512;   ta.R[3] = 512;  ta.C[3] = 512;
    ta.src[4] = a1_wo; ta.dst[4] = wT_a1o;                ta.R[4] = 512;  ta.C[4] = 512;
    ta.src[5] = a2_wo; ta.dst[5] = wT_a2o;                ta.R[5] = 512;  ta.C[5] = 512;
    ta.src[6] = ff_w1; ta.dst[6] = wT_ff1;                ta.R[6] = 512;  ta.C[6] = 4096;
    ta.src[7] = ff_w2; ta.dst[7] = wT_ff2;                ta.R[7] = 2048; ta.C[7] = 512;
    ta.start[0] = 0;
    for (int s = 0; s < 8; s++)
        ta.start[s + 1] = ta.start[s] + (ta.C[s] >> 5) * (ta.R[s] >> 5);
    transpose_multi<<<ta.start[8], 256, 0, stream>>>(ta);

    // === attention 1 (self) ===
    ln_kernel<<<2048, 256, 0, stream>>>(x, sa_w, sa_b, xn);
    gemm_qv<<<dim3(64, 8), 256, 0, stream>>>(xn, wT_a1qv, a1_bq, a1_bv, qbuf, vtp, aab, 512);
    attn_mfma<<<512, 256, 0, stream>>>(qbuf, vtp, aab, attn_o);
    gemm_rect<2><<<dim3(64, 8), 256, 0, stream>>>(attn_o, wT_a1o, a1_bo, x, x_res, 8192, 512, 512);

    // === attention 2 ("cross", k=q, v from x) ===
    ln_kernel<<<2048, 256, 0, stream>>>(x_res, ca_w, ca_b, xn);
    gemm_qv<<<dim3(64, 8), 256, 0, stream>>>(xn, wT_a2qv, a2_bq, a2_bv, qbuf, vtp, aab, 512);
    attn_mfma<<<512, 256, 0, stream>>>(qbuf, vtp, aab, attn_o);
    gemm_rect<2><<<dim3(64, 8), 256, 0, stream>>>(attn_o, wT_a2o, a2_bo, x_res, x_res, 8192, 512, 512);

    // === GEGLU FFN (geglu fused into ff1; ff2 on BK=64 path) ===
    ln_kernel<<<2048, 256, 0, stream>>>(x_res, ffn_w, ffn_b, xn);
    gemm_ff1<<<dim3(64, 32), 256, 0, stream>>>(xn, wT_ff1, ff_b1, gbuf, 512);
    gemm_rect64<<<dim3(64, 8), 256, 0, stream>>>(gbuf, wT_ff2, ff_b2, x_res, (float*)d_out, 512, 2048);
}